// Round 9
// baseline (112.750 us; speedup 1.0000x reference)
//
#include <hip/hip_runtime.h>

#define CIN  4096
#define OUTR 16384
#define NPOS 4096

typedef __attribute__((ext_vector_type(8))) short    bf16x8;
typedef __attribute__((ext_vector_type(4))) float    f32x4;
typedef __attribute__((ext_vector_type(4))) _Float16 h4v;

__device__ inline short bf16rne(float f) {
    unsigned u = __float_as_uint(f);
    return (short)((u + 0x7FFFu + ((u >> 16) & 1u)) >> 16);
}
__device__ inline bf16x8 pack8(float4 a, float4 b) {
    bf16x8 v;
    v[0]=bf16rne(a.x); v[1]=bf16rne(a.y); v[2]=bf16rne(a.z); v[3]=bf16rne(a.w);
    v[4]=bf16rne(b.x); v[5]=bf16rne(b.y); v[6]=bf16rne(b.z); v[7]=bf16rne(b.w);
    return v;
}

// ---------------- Kernel 0: pack W (f32 -> bf16), Wp[16384][64] ----------------
__global__ __launch_bounds__(256) void fc2_pack(const float* __restrict__ W, short* __restrict__ Wp) {
    int u = blockIdx.x * 256 + threadIdx.x;       // 131072 threads, 8 elems each
    int row = u >> 3, c8 = u & 7;
    const float* s = W + (size_t)row * 64 + c8 * 8;
    float4 a = *(const float4*)s, b = *(const float4*)(s + 4);
    *(bf16x8*)(Wp + (size_t)row * 64 + c8 * 8) = pack8(a, b);
}

// Shared geometry for A/B:
// block = 512 thr (8 waves: wch=wid&3 channel-sub, wpos=wid>>2 pos-sub)
// block (j, pos-tile 32): out-ch Oj=[256j,+256), groups g_r=16r+j, K=64 each.
// grid 2048 = 16 j x 128 pos-tiles; XCD-chunked: each XCD owns 2 whole j's.

// ---------------- Kernel A: stats + s extraction (no y store) ----------------
__global__ __launch_bounds__(512, 4) void fc2_statsA(
    const float* __restrict__ In,    // [NPOS][CIN]
    const short* __restrict__ Wp,    // [OUTR][64] bf16
    const float* __restrict__ Bias,  // [OUTR]
    _Float16* __restrict__ Sb,       // [NPOS][4096] f16: s[pos][o']
    float* __restrict__ Stats)       // [NPOS][16 j][8]: pd[4],pa[4]
{
    __shared__ __align__(16) char ldsb[53248];
    char* lds_w  = ldsb;             // [256 ch][128B] bf16 swizzled; s_lds after GEMMs
    char* lds_in = ldsb + 32768;     // 4 x [32 pos][128B] bf16 swizzled
    float* redbuf = (float*)(ldsb + 49152);  // [4 wch][2 wpos][16][8]

    const int t = threadIdx.x;
    const int swz = ((blockIdx.x & 7) << 8) + (blockIdx.x >> 3);
    const int j = swz >> 7, pos0 = (swz & 127) * 32;
    const int wid = t >> 6, l = t & 63, lr = l & 15, lh = l >> 4;
    const int wch = wid & 3, wpos = wid >> 2;
    const int prow = wpos * 16 + lr;   // this thread's position (0..31)

    // stage In: 4 group-slices [32 pos][64 c] -> bf16 LDS
#pragma unroll
    for (int it = 0; it < 2; it++) {
        int u = it * 512 + t, r = u >> 8, p = (u >> 3) & 31, c8 = u & 7;
        const float* src = In + (size_t)(pos0 + p) * CIN + (16 * r + j) * 64 + c8 * 8;
        float4 a = *(const float4*)src, b = *(const float4*)(src + 4);
        *(bf16x8*)(lds_in + r * 4096 + p * 128 + ((c8 * 16) ^ ((p & 7) << 4))) = pack8(a, b);
    }
    // stage W group g0 = j
#pragma unroll
    for (int it = 0; it < 4; it++) {
        int u = it * 512 + t, row = u >> 3, c8 = u & 7;
        *(bf16x8*)(lds_w + row * 128 + ((c8 * 16) ^ ((row & 7) << 4))) =
            *(const bf16x8*)(Wp + (size_t)(j * 256 + row) * 64 + c8 * 8);
    }
    __syncthreads();

    f32x4 xacc[4][4];   // [r][m], q=0..3 channels
#pragma unroll
    for (int r = 0; r < 4; r++) {
        // prefetch next group's W into regs (latency hides under MFMA)
        bf16x8 wreg[4];
        if (r < 3) {
            int gn = 16 * (r + 1) + j;
#pragma unroll
            for (int q4 = 0; q4 < 4; q4++)
                wreg[q4] = *(const bf16x8*)(Wp + (size_t)(gn * 256 + q4 * 64 + (t >> 3)) * 64 + (t & 7) * 8);
        }
#pragma unroll
        for (int m = 0; m < 4; m++) xacc[r][m] = (f32x4){0.f, 0.f, 0.f, 0.f};
#pragma unroll
        for (int kk = 0; kk < 2; kk++) {
            int ksl = (kk * 4 + lh) * 16;
            bf16x8 bfr = *(const bf16x8*)(lds_in + r * 4096 + prow * 128 + (ksl ^ ((prow & 7) << 4)));
#pragma unroll
            for (int m = 0; m < 4; m++) {
                int row = wch * 64 + m * 16 + lr;
                bf16x8 afr = *(const bf16x8*)(lds_w + row * 128 + (ksl ^ ((row & 7) << 4)));
                xacc[r][m] = __builtin_amdgcn_mfma_f32_16x16x32_bf16(afr, bfr, xacc[r][m], 0, 0, 0);
            }
        }
#pragma unroll
        for (int m = 0; m < 4; m++) {
            f32x4 bb = *(const f32x4*)(Bias + (16 * r + j) * 256 + wch * 64 + m * 16 + lh * 4);
            xacc[r][m] += bb;
        }
        __syncthreads();              // lds_w reads done
        if (r < 3) {
            int row0 = t >> 3, c8 = t & 7;
#pragma unroll
            for (int q4 = 0; q4 < 4; q4++) {
                int row = q4 * 64 + row0;
                *(bf16x8*)(lds_w + row * 128 + ((c8 * 16) ^ ((row & 7) << 4))) = wreg[q4];
            }
            __syncthreads();          // next W visible
        }
    }

    // per-thread stats (one position, 16 channels per r)
    float pd[4] = {0,0,0,0}, pa[4] = {0,0,0,0};
#pragma unroll
    for (int m = 0; m < 4; m++)
#pragma unroll
        for (int q = 0; q < 4; q++) {
            float xs = xacc[0][m][q] + xacc[1][m][q] + xacc[2][m][q] + xacc[3][m][q];
#pragma unroll
            for (int r = 0; r < 4; r++) {
                float e = __expf(xacc[r][m][q]);
                pd[r] += e; pa[r] += e * xs;
            }
        }
#pragma unroll
    for (int r = 0; r < 4; r++) {
        pd[r] += __shfl_xor(pd[r], 16); pd[r] += __shfl_xor(pd[r], 32);
        pa[r] += __shfl_xor(pa[r], 16); pa[r] += __shfl_xor(pa[r], 32);
    }
    if (lh == 0) {
        float* rb = redbuf + ((wch * 2 + wpos) * 16 + lr) * 8;
#pragma unroll
        for (int r = 0; r < 4; r++) { rb[r] = pd[r]; rb[4 + r] = pa[r]; }
    }
    // s extraction: s[o'=r*1024+j*64+ch'] = x[o,r] at q==0; stage into lds_w region (f16)
#pragma unroll
    for (int r = 0; r < 4; r++)
#pragma unroll
        for (int m = 0; m < 4; m++) {
            unsigned off = (unsigned)(prow * 512 + r * 128 + (wch * 16 + m * 4 + lh) * 2);
            off ^= (unsigned)((prow & 7) << 4);
            *(_Float16*)(ldsb + off) = (_Float16)xacc[r][m][0];
        }
    __syncthreads();

    if (t < 256) {
        int wp2 = t >> 7, lr2 = (t >> 3) & 15, slot = t & 7;
        float v = 0.f;
#pragma unroll
        for (int c = 0; c < 4; c++) v += redbuf[((c * 2 + wp2) * 16 + lr2) * 8 + slot];
        Stats[(size_t)(pos0 + wp2 * 16 + lr2) * 128 + j * 8 + slot] = v;
    }
    // coop store s tile: [32 pos][4 r][64 ch'] f16 = 16 KB
#pragma unroll
    for (int it = 0; it < 2; it++) {
        int u = it * 512 + t, sp = u >> 5, rr = (u >> 3) & 3, c8 = u & 7;
        unsigned off = (unsigned)(sp * 512 + rr * 128 + c8 * 16) ^ ((unsigned)((sp & 7) << 4));
        *(bf16x8*)((_Float16*)Sb + (size_t)(pos0 + sp) * 4096 + rr * 1024 + j * 64 + c8 * 8) =
            *(const bf16x8*)(ldsb + off);
    }
}

// ---------------- Kernel B: recompute GEMMs + output ----------------
__global__ __launch_bounds__(512, 4) void fc2_outB(
    const float* __restrict__ In,
    const short* __restrict__ Wp,
    const float* __restrict__ Bias,
    const _Float16* __restrict__ Sb,
    const float* __restrict__ Stats,
    float* __restrict__ Out)         // [NPOS][4096]
{
    __shared__ __align__(16) char ldsb[50176];
    char* lds_w  = ldsb;
    char* lds_in = ldsb + 32768;
    float* kraw = (float*)(ldsb + 49152);   // [32 pos][8]

    const int t = threadIdx.x;
    const int swz = ((blockIdx.x & 7) << 8) + (blockIdx.x >> 3);
    const int j = swz >> 7, pos0 = (swz & 127) * 32;
    const int wid = t >> 6, l = t & 63, lr = l & 15, lh = l >> 4;
    const int wch = wid & 3, wpos = wid >> 2;
    const int prow = wpos * 16 + lr;

    // early: reduce stats over j' (values land before first barrier)
    float ksum = 0.f;
    if (t < 256) {
        const float* bp = Stats + (size_t)(pos0 + (t >> 3)) * 128 + (t & 7);
#pragma unroll
        for (int j2 = 0; j2 < 16; j2++) ksum += bp[j2 * 8];
    }
    // early: s tile into regs (32 pos x 256 ch f16 = 16/thread)
    const _Float16* sgp = Sb + (size_t)(pos0 + (t >> 4)) * 4096 + j * 256 + (t & 15) * 16;
    bf16x8 sreg0 = *(const bf16x8*)sgp;
    bf16x8 sreg1 = *(const bf16x8*)(sgp + 8);

    // stage In + W0 (identical to A)
#pragma unroll
    for (int it = 0; it < 2; it++) {
        int u = it * 512 + t, r = u >> 8, p = (u >> 3) & 31, c8 = u & 7;
        const float* src = In + (size_t)(pos0 + p) * CIN + (16 * r + j) * 64 + c8 * 8;
        float4 a = *(const float4*)src, b = *(const float4*)(src + 4);
        *(bf16x8*)(lds_in + r * 4096 + p * 128 + ((c8 * 16) ^ ((p & 7) << 4))) = pack8(a, b);
    }
#pragma unroll
    for (int it = 0; it < 4; it++) {
        int u = it * 512 + t, row = u >> 3, c8 = u & 7;
        *(bf16x8*)(lds_w + row * 128 + ((c8 * 16) ^ ((row & 7) << 4))) =
            *(const bf16x8*)(Wp + (size_t)(j * 256 + row) * 64 + c8 * 8);
    }
    if (t < 256) kraw[t] = ksum;
    __syncthreads();

    float kr[4];
#pragma unroll
    for (int r = 0; r < 4; r++) kr[r] = kraw[prow * 8 + 4 + r] / kraw[prow * 8 + r];

    f32x4 oacc[4];
#pragma unroll
    for (int m = 0; m < 4; m++) oacc[m] = (f32x4){0.f, 0.f, 0.f, 0.f};

#pragma unroll
    for (int r = 0; r < 4; r++) {
        bf16x8 wreg[4];
        if (r < 3) {
            int gn = 16 * (r + 1) + j;
#pragma unroll
            for (int q4 = 0; q4 < 4; q4++)
                wreg[q4] = *(const bf16x8*)(Wp + (size_t)(gn * 256 + q4 * 64 + (t >> 3)) * 64 + (t & 7) * 8);
        }
        f32x4 xf[4];
#pragma unroll
        for (int m = 0; m < 4; m++) xf[m] = (f32x4){0.f, 0.f, 0.f, 0.f};
#pragma unroll
        for (int kk = 0; kk < 2; kk++) {
            int ksl = (kk * 4 + lh) * 16;
            bf16x8 bfr = *(const bf16x8*)(lds_in + r * 4096 + prow * 128 + (ksl ^ ((prow & 7) << 4)));
#pragma unroll
            for (int m = 0; m < 4; m++) {
                int row = wch * 64 + m * 16 + lr;
                bf16x8 afr = *(const bf16x8*)(lds_w + row * 128 + (ksl ^ ((row & 7) << 4)));
                xf[m] = __builtin_amdgcn_mfma_f32_16x16x32_bf16(afr, bfr, xf[m], 0, 0, 0);
            }
        }
#pragma unroll
        for (int m = 0; m < 4; m++) {
            f32x4 bb = *(const f32x4*)(Bias + (16 * r + j) * 256 + wch * 64 + m * 16 + lh * 4);
            xf[m] += bb;
#pragma unroll
            for (int q = 0; q < 4; q++) oacc[m][q] += xf[m][q] * kr[r];
        }
        __syncthreads();
        if (r < 3) {
            int row0 = t >> 3, c8 = t & 7;
#pragma unroll
            for (int q4 = 0; q4 < 4; q4++) {
                int row = q4 * 64 + row0;
                *(bf16x8*)(lds_w + row * 128 + ((c8 * 16) ^ ((row & 7) << 4))) = wreg[q4];
            }
            __syncthreads();
        }
    }

    // s regs -> lds_w region [32 pos][256 ch f16 = 512B] swizzled
    {
        int spp = t >> 4, seg = t & 15;
        unsigned b0 = (unsigned)(spp * 512 + seg * 32);
        *(bf16x8*)(ldsb + (b0 ^ ((unsigned)((spp & 7) << 4)))) = sreg0;
        *(bf16x8*)(ldsb + ((b0 + 16) ^ ((unsigned)((spp & 7) << 4)))) = sreg1;
    }
    __syncthreads();

    // epilogue: out = s + sum_r x*kr, direct f32x4 stores
#pragma unroll
    for (int m = 0; m < 4; m++) {
        int ch = wch * 64 + m * 16 + lh * 4;
        unsigned off = ((unsigned)(prow * 512 + ch * 2)) ^ ((unsigned)((prow & 7) << 4));
        h4v sv = *(const h4v*)(ldsb + off);
        f32x4 ov;
#pragma unroll
        for (int q = 0; q < 4; q++) ov[q] = (float)sv[q] + oacc[m][q];
        *(f32x4*)(Out + (size_t)(pos0 + prow) * CIN + j * 256 + ch) = ov;
    }
}

extern "C" void kernel_launch(void* const* d_in, const int* in_sizes, int n_in,
                              void* d_out, int out_size, void* d_ws, size_t ws_size,
                              hipStream_t stream) {
    const float* In   = (const float*)d_in[0];
    const float* W    = (const float*)d_in[1];
    const float* Bias = (const float*)d_in[2];
    float* Out = (float*)d_out;

    char* ws = (char*)d_ws;
    short*     Wp    = (short*)ws;                    // 2 MB
    _Float16*  Sb    = (_Float16*)(ws + (4u << 20));  // 32 MB
    float*     Stats = (float*)(ws + (40u << 20));    // 2 MB

    fc2_pack  <<<dim3(512),  dim3(256), 0, stream>>>(W, Wp);
    fc2_statsA<<<dim3(2048), dim3(512), 0, stream>>>(In, Wp, Bias, Sb, Stats);
    fc2_outB  <<<dim3(2048), dim3(512), 0, stream>>>(In, Wp, Bias, Sb, Stats, Out);
}

// Round 10
// 100.204 us; speedup vs baseline: 1.1252x; 1.1252x over previous
//
#include <hip/hip_runtime.h>

#define CIN  4096
#define OUTR 16384
#define NPOS 4096

typedef __attribute__((ext_vector_type(8))) short    bf16x8;
typedef __attribute__((ext_vector_type(4))) float    f32x4;
typedef __attribute__((ext_vector_type(4))) _Float16 h4v;

__device__ inline short bf16rne(float f) {
    unsigned u = __float_as_uint(f);
    return (short)((u + 0x7FFFu + ((u >> 16) & 1u)) >> 16);
}
__device__ inline bf16x8 pack8(float4 a, float4 b) {
    bf16x8 v;
    v[0]=bf16rne(a.x); v[1]=bf16rne(a.y); v[2]=bf16rne(a.z); v[3]=bf16rne(a.w);
    v[4]=bf16rne(b.x); v[5]=bf16rne(b.y); v[6]=bf16rne(b.z); v[7]=bf16rne(b.w);
    return v;
}

// ---------------- Kernel 0: pack W (f32 -> bf16), Wp[16384][64] ----------------
__global__ __launch_bounds__(256) void fc2_pack(const float* __restrict__ W, short* __restrict__ Wp) {
    int u = blockIdx.x * 256 + threadIdx.x;
    int row = u >> 3, c8 = u & 7;
    const float* s = W + (size_t)row * 64 + c8 * 8;
    float4 a = *(const float4*)s, b = *(const float4*)(s + 4);
    *(bf16x8*)(Wp + (size_t)row * 64 + c8 * 8) = pack8(a, b);
}

// Shared geometry: block = 512 thr (8 waves: wch=wid&3, wpos=wid>>2);
// block (j, pos-tile 32): out-ch Oj=[256j,+256), groups g_r=16r+j, K=64.
// grid 2048 = 16 j x 128 pos-tiles; XCD-chunked (2048=8*256, bijective).

// ---------------- Kernel A: stats + s extraction (no y store) ----------------
__global__ __launch_bounds__(512, 2) void fc2_statsA(
    const float* __restrict__ In,    // [NPOS][CIN]
    const short* __restrict__ Wp,    // [OUTR][64] bf16
    const float* __restrict__ Bias,  // [OUTR]
    _Float16* __restrict__ Sb,       // [NPOS][4096] f16
    float* __restrict__ Stats)       // [NPOS][16 j][8]: pd[4],pa[4]
{
    __shared__ __align__(16) char ldsb[53248];
    char* lds_w  = ldsb;             // [256 ch][128B] bf16 swizzled; s_lds after GEMMs
    char* lds_in = ldsb + 32768;     // 4 x [32 pos][128B] bf16 swizzled
    float* redbuf = (float*)(ldsb + 49152);  // [8 wave][16 pos][8]

    const int t = threadIdx.x;
    const int swz = ((blockIdx.x & 7) << 8) + (blockIdx.x >> 3);
    const int j = swz >> 7, pos0 = (swz & 127) * 32;
    const int wid = t >> 6, l = t & 63, lr = l & 15, lh = l >> 4;
    const int wch = wid & 3, wpos = wid >> 2;
    const int prow = wpos * 16 + lr;

    // stage In: 4 group-slices [32 pos][64 c] -> bf16 LDS
#pragma unroll
    for (int it = 0; it < 2; it++) {
        int u = it * 512 + t, r = u >> 8, p = (u >> 3) & 31, c8 = u & 7;
        const float* src = In + (size_t)(pos0 + p) * CIN + (16 * r + j) * 64 + c8 * 8;
        float4 a = *(const float4*)src, b = *(const float4*)(src + 4);
        *(bf16x8*)(lds_in + r * 4096 + p * 128 + ((c8 * 16) ^ ((p & 7) << 4))) = pack8(a, b);
    }
    // stage W group g0 = j
#pragma unroll
    for (int it = 0; it < 4; it++) {
        int u = it * 512 + t, row = u >> 3, c8 = u & 7;
        *(bf16x8*)(lds_w + row * 128 + ((c8 * 16) ^ ((row & 7) << 4))) =
            *(const bf16x8*)(Wp + (size_t)(j * 256 + row) * 64 + c8 * 8);
    }
    __syncthreads();

    h4v xh[4][4];   // x compressed to f16: [r][m], 4 ch each  (32 VGPR)
#pragma unroll
    for (int r = 0; r < 4; r++) {
        bf16x8 wreg[4];
        if (r < 3) {
            int gn = 16 * (r + 1) + j;
#pragma unroll
            for (int q4 = 0; q4 < 4; q4++)
                wreg[q4] = *(const bf16x8*)(Wp + (size_t)(gn * 256 + q4 * 64 + (t >> 3)) * 64 + (t & 7) * 8);
        }
        f32x4 xf[4];
#pragma unroll
        for (int m = 0; m < 4; m++) xf[m] = (f32x4){0.f, 0.f, 0.f, 0.f};
#pragma unroll
        for (int kk = 0; kk < 2; kk++) {
            int ksl = (kk * 4 + lh) * 16;
            bf16x8 bfr = *(const bf16x8*)(lds_in + r * 4096 + prow * 128 + (ksl ^ ((prow & 7) << 4)));
#pragma unroll
            for (int m = 0; m < 4; m++) {
                int row = wch * 64 + m * 16 + lr;
                bf16x8 afr = *(const bf16x8*)(lds_w + row * 128 + (ksl ^ ((row & 7) << 4)));
                xf[m] = __builtin_amdgcn_mfma_f32_16x16x32_bf16(afr, bfr, xf[m], 0, 0, 0);
            }
        }
#pragma unroll
        for (int m = 0; m < 4; m++) {
            f32x4 bb = *(const f32x4*)(Bias + (16 * r + j) * 256 + wch * 64 + m * 16 + lh * 4);
            xf[m] += bb;
#pragma unroll
            for (int q = 0; q < 4; q++) xh[r][m][q] = (_Float16)xf[m][q];
        }
        __syncthreads();
        if (r < 3) {
            int row0 = t >> 3, c8 = t & 7;
#pragma unroll
            for (int q4 = 0; q4 < 4; q4++) {
                int row = q4 * 64 + row0;
                *(bf16x8*)(lds_w + row * 128 + ((c8 * 16) ^ ((row & 7) << 4))) = wreg[q4];
            }
            __syncthreads();
        }
    }

    // stats from f16 x (numerically = old Y-roundtrip path)
    float pd[4] = {0,0,0,0}, pa[4] = {0,0,0,0};
#pragma unroll
    for (int m = 0; m < 4; m++)
#pragma unroll
        for (int q = 0; q < 4; q++) {
            float x0 = (float)xh[0][m][q], x1 = (float)xh[1][m][q];
            float x2 = (float)xh[2][m][q], x3 = (float)xh[3][m][q];
            float xs = x0 + x1 + x2 + x3;
            float e0 = __expf(x0), e1 = __expf(x1), e2 = __expf(x2), e3 = __expf(x3);
            pd[0] += e0; pa[0] += e0 * xs;
            pd[1] += e1; pa[1] += e1 * xs;
            pd[2] += e2; pa[2] += e2 * xs;
            pd[3] += e3; pa[3] += e3 * xs;
        }
#pragma unroll
    for (int r = 0; r < 4; r++) {
        pd[r] += __shfl_xor(pd[r], 16); pd[r] += __shfl_xor(pd[r], 32);
        pa[r] += __shfl_xor(pa[r], 16); pa[r] += __shfl_xor(pa[r], 32);
    }
    if (lh == 0) {
        float* rb = redbuf + ((wch * 2 + wpos) * 16 + lr) * 8;
#pragma unroll
        for (int r = 0; r < 4; r++) { rb[r] = pd[r]; rb[4 + r] = pa[r]; }
    }
    // s extraction: q==0 elements -> lds (f16), swizzled
#pragma unroll
    for (int r = 0; r < 4; r++)
#pragma unroll
        for (int m = 0; m < 4; m++) {
            unsigned off = (unsigned)(prow * 512 + r * 128 + (wch * 16 + m * 4 + lh) * 2);
            off ^= (unsigned)((prow & 7) << 4);
            *(_Float16*)(ldsb + off) = xh[r][m][0];
        }
    __syncthreads();

    if (t < 256) {
        int wp2 = t >> 7, lr2 = (t >> 3) & 15, slot = t & 7;
        float v = 0.f;
#pragma unroll
        for (int c = 0; c < 4; c++) v += redbuf[((c * 2 + wp2) * 16 + lr2) * 8 + slot];
        Stats[(size_t)(pos0 + wp2 * 16 + lr2) * 128 + j * 8 + slot] = v;
    }
    // coop store s tile: [32 pos][4 r][64 ch'] f16
#pragma unroll
    for (int it = 0; it < 2; it++) {
        int u = it * 512 + t, sp = u >> 5, rr = (u >> 3) & 3, c8 = u & 7;
        unsigned off = (unsigned)(sp * 512 + rr * 128 + c8 * 16) ^ ((unsigned)((sp & 7) << 4));
        *(bf16x8*)((_Float16*)Sb + (size_t)(pos0 + sp) * 4096 + rr * 1024 + j * 64 + c8 * 8) =
            *(const bf16x8*)(ldsb + off);
    }
}

// ---------------- Kernel B: recompute GEMMs + output ----------------
__global__ __launch_bounds__(512, 2) void fc2_outB(
    const float* __restrict__ In,
    const short* __restrict__ Wp,
    const float* __restrict__ Bias,
    const _Float16* __restrict__ Sb,
    const float* __restrict__ Stats,
    float* __restrict__ Out)         // [NPOS][4096]
{
    __shared__ __align__(16) char ldsb[50176];
    char* lds_w  = ldsb;
    char* lds_in = ldsb + 32768;
    float* kraw = (float*)(ldsb + 49152);   // [32 pos][8]

    const int t = threadIdx.x;
    const int swz = ((blockIdx.x & 7) << 8) + (blockIdx.x >> 3);
    const int j = swz >> 7, pos0 = (swz & 127) * 32;
    const int wid = t >> 6, l = t & 63, lr = l & 15, lh = l >> 4;
    const int wch = wid & 3, wpos = wid >> 2;
    const int prow = wpos * 16 + lr;

    // early: reduce stats over j'
    float ksum = 0.f;
    if (t < 256) {
        const float* bp = Stats + (size_t)(pos0 + (t >> 3)) * 128 + (t & 7);
#pragma unroll
        for (int j2 = 0; j2 < 16; j2++) ksum += bp[j2 * 8];
    }
    // early: s tile into regs
    const _Float16* sgp = Sb + (size_t)(pos0 + (t >> 4)) * 4096 + j * 256 + (t & 15) * 16;
    bf16x8 sreg0 = *(const bf16x8*)sgp;
    bf16x8 sreg1 = *(const bf16x8*)(sgp + 8);

    // stage In + W0 (identical to A)
#pragma unroll
    for (int it = 0; it < 2; it++) {
        int u = it * 512 + t, r = u >> 8, p = (u >> 3) & 31, c8 = u & 7;
        const float* src = In + (size_t)(pos0 + p) * CIN + (16 * r + j) * 64 + c8 * 8;
        float4 a = *(const float4*)src, b = *(const float4*)(src + 4);
        *(bf16x8*)(lds_in + r * 4096 + p * 128 + ((c8 * 16) ^ ((p & 7) << 4))) = pack8(a, b);
    }
#pragma unroll
    for (int it = 0; it < 4; it++) {
        int u = it * 512 + t, row = u >> 3, c8 = u & 7;
        *(bf16x8*)(lds_w + row * 128 + ((c8 * 16) ^ ((row & 7) << 4))) =
            *(const bf16x8*)(Wp + (size_t)(j * 256 + row) * 64 + c8 * 8);
    }
    if (t < 256) kraw[t] = ksum;
    __syncthreads();

    float kr[4];
#pragma unroll
    for (int r = 0; r < 4; r++) kr[r] = kraw[prow * 8 + 4 + r] / kraw[prow * 8 + r];

    f32x4 oacc[4];
#pragma unroll
    for (int m = 0; m < 4; m++) oacc[m] = (f32x4){0.f, 0.f, 0.f, 0.f};

#pragma unroll
    for (int r = 0; r < 4; r++) {
        bf16x8 wreg[4];
        if (r < 3) {
            int gn = 16 * (r + 1) + j;
#pragma unroll
            for (int q4 = 0; q4 < 4; q4++)
                wreg[q4] = *(const bf16x8*)(Wp + (size_t)(gn * 256 + q4 * 64 + (t >> 3)) * 64 + (t & 7) * 8);
        }
        f32x4 xf[4];
#pragma unroll
        for (int m = 0; m < 4; m++) xf[m] = (f32x4){0.f, 0.f, 0.f, 0.f};
#pragma unroll
        for (int kk = 0; kk < 2; kk++) {
            int ksl = (kk * 4 + lh) * 16;
            bf16x8 bfr = *(const bf16x8*)(lds_in + r * 4096 + prow * 128 + (ksl ^ ((prow & 7) << 4)));
#pragma unroll
            for (int m = 0; m < 4; m++) {
                int row = wch * 64 + m * 16 + lr;
                bf16x8 afr = *(const bf16x8*)(lds_w + row * 128 + (ksl ^ ((row & 7) << 4)));
                xf[m] = __builtin_amdgcn_mfma_f32_16x16x32_bf16(afr, bfr, xf[m], 0, 0, 0);
            }
        }
#pragma unroll
        for (int m = 0; m < 4; m++) {
            f32x4 bb = *(const f32x4*)(Bias + (16 * r + j) * 256 + wch * 64 + m * 16 + lh * 4);
            xf[m] += bb;
#pragma unroll
            for (int q = 0; q < 4; q++) oacc[m][q] += xf[m][q] * kr[r];
        }
        __syncthreads();
        if (r < 3) {
            int row0 = t >> 3, c8 = t & 7;
#pragma unroll
            for (int q4 = 0; q4 < 4; q4++) {
                int row = q4 * 64 + row0;
                *(bf16x8*)(lds_w + row * 128 + ((c8 * 16) ^ ((row & 7) << 4))) = wreg[q4];
            }
            __syncthreads();
        }
    }

    // s regs -> lds [32 pos][512B] swizzled
    {
        int spp = t >> 4, seg = t & 15;
        unsigned b0 = (unsigned)(spp * 512 + seg * 32);
        *(bf16x8*)(ldsb + (b0 ^ ((unsigned)((spp & 7) << 4)))) = sreg0;
        *(bf16x8*)(ldsb + ((b0 + 16) ^ ((unsigned)((spp & 7) << 4)))) = sreg1;
    }
    __syncthreads();

    // epilogue: out = s + sum_r x*kr
#pragma unroll
    for (int m = 0; m < 4; m++) {
        int ch = wch * 64 + m * 16 + lh * 4;
        unsigned off = ((unsigned)(prow * 512 + ch * 2)) ^ ((unsigned)((prow & 7) << 4));
        h4v sv = *(const h4v*)(ldsb + off);
        f32x4 ov;
#pragma unroll
        for (int q = 0; q < 4; q++) ov[q] = (float)sv[q] + oacc[m][q];
        *(f32x4*)(Out + (size_t)(pos0 + prow) * CIN + j * 256 + ch) = ov;
    }
}

extern "C" void kernel_launch(void* const* d_in, const int* in_sizes, int n_in,
                              void* d_out, int out_size, void* d_ws, size_t ws_size,
                              hipStream_t stream) {
    const float* In   = (const float*)d_in[0];
    const float* W    = (const float*)d_in[1];
    const float* Bias = (const float*)d_in[2];
    float* Out = (float*)d_out;

    char* ws = (char*)d_ws;
    short*     Wp    = (short*)ws;                    // 2 MB
    _Float16*  Sb    = (_Float16*)(ws + (4u << 20));  // 32 MB
    float*     Stats = (float*)(ws + (40u << 20));    // 2 MB

    fc2_pack  <<<dim3(512),  dim3(256), 0, stream>>>(W, Wp);
    fc2_statsA<<<dim3(2048), dim3(512), 0, stream>>>(In, Wp, Bias, Sb, Stats);
    fc2_outB  <<<dim3(2048), dim3(512), 0, stream>>>(In, Wp, Bias, Sb, Stats, Out);
}

// Round 11
// 99.563 us; speedup vs baseline: 1.1324x; 1.0064x over previous
//
#include <hip/hip_runtime.h>

#define CIN  4096
#define OUTR 16384
#define NPOS 4096

typedef __attribute__((ext_vector_type(8))) short    bf16x8;
typedef __attribute__((ext_vector_type(4))) float    f32x4;
typedef __attribute__((ext_vector_type(4))) _Float16 h4v;

__device__ inline short bf16rne(float f) {
    unsigned u = __float_as_uint(f);
    return (short)((u + 0x7FFFu + ((u >> 16) & 1u)) >> 16);
}
__device__ inline bf16x8 pack8(float4 a, float4 b) {
    bf16x8 v;
    v[0]=bf16rne(a.x); v[1]=bf16rne(a.y); v[2]=bf16rne(a.z); v[3]=bf16rne(a.w);
    v[4]=bf16rne(b.x); v[5]=bf16rne(b.y); v[6]=bf16rne(b.z); v[7]=bf16rne(b.w);
    return v;
}

// LDS-only barrier: global stores stay in flight across it (proven R6/R7)
__device__ inline void barrier_lgkm() {
    asm volatile("s_waitcnt lgkmcnt(0)" ::: "memory");
    __builtin_amdgcn_sched_barrier(0);
    __builtin_amdgcn_s_barrier();
    __builtin_amdgcn_sched_barrier(0);
}

// ---------------- pack W f32 -> bf16 ----------------
__global__ __launch_bounds__(256) void fc2_pack(const float* __restrict__ W, short* __restrict__ Wp) {
    int u = blockIdx.x * 256 + threadIdx.x;
    int row = u >> 3, c8 = u & 7;
    const float* s = W + (size_t)row * 64 + c8 * 8;
    float4 a = *(const float4*)s, b = *(const float4*)(s + 4);
    *(bf16x8*)(Wp + (size_t)row * 64 + c8 * 8) = pack8(a, b);
}

// Shared geometry A/B: 512 blocks = 16 j x 4 qh x 8 stripes(512 pos = 16 tiles of 32).
// Block: out-ch [256j+64qh, +64), groups g_r=16r+j (K=64 each), all 4 r in-thread.
// 8 waves: m = w&3 (16-ch m-tile), n = w>>2 (16-pos half). W-frags in regs (afr).
// XCD swizzle: 512 = 8*64, each XCD owns 2 whole j's.

#define GEOM_IDS \
    const int t = threadIdx.x; \
    const int swz = ((blockIdx.x & 7) << 6) + (blockIdx.x >> 3); \
    const int j = swz >> 5, qh = (swz >> 3) & 3, stripe = swz & 7; \
    const int pos0 = stripe * 512; \
    const int w = t >> 6, l = t & 63, lr = l & 15, lh = l >> 4; \
    const int m = w & 3, n = w >> 2;

// In-tile staging: units idx in [0,1024): c8=idx&7, p=(idx>>3)&31, r=idx>>8
#define IN_SRC(ti_, idx_) (In + (size_t)(pos0 + (ti_) * 32 + (((idx_) >> 3) & 31)) * CIN \
                               + (16 * ((idx_) >> 8) + j) * 64 + ((idx_) & 7) * 8)
#define IN_DST(idx_) (lds_in + ((((idx_) >> 8) * 32 + (((idx_) >> 3) & 31)) * 128) \
                             + ((((idx_) & 7) * 16) ^ (((((idx_) >> 3) & 7)) << 4)))

// ---------------- Kernel A: softmax stats + s extraction ----------------
__global__ __launch_bounds__(512, 2) void fc2_statsA(
    const float* __restrict__ In,    // [NPOS][CIN]
    const short* __restrict__ Wp,    // [OUTR][64] bf16
    const float* __restrict__ Bias,  // [OUTR]
    _Float16* __restrict__ Sb,       // [NPOS][4096]: s by output-channel
    float* __restrict__ Stats)       // [NPOS][64 jq][8]: pd[4], pa[4]
{
    __shared__ __align__(16) char lds_in[16384];       // [4r][32p][128B] swizzled
    __shared__ float    redbuf[4][32][8];              // 4 KB
    __shared__ _Float16 sbuf[32][4][16];               // 4 KB
    GEOM_IDS

    // W fragments (all 4 groups) -> regs; Wp is L2-resident
    bf16x8 afr[4][2];
#pragma unroll
    for (int r = 0; r < 4; r++)
#pragma unroll
        for (int kk = 0; kk < 2; kk++)
            afr[r][kk] = *(const bf16x8*)(Wp +
                (size_t)((16 * r + j) * 256 + 64 * qh + m * 16 + lr) * 64 + kk * 32 + lh * 8);
    f32x4 bias[4];
#pragma unroll
    for (int r = 0; r < 4; r++)
        bias[r] = *(const f32x4*)(Bias + (16 * r + j) * 256 + 64 * qh + m * 16 + lh * 4);

    // stage In tile 0 (2 units/thread)
#pragma unroll
    for (int it = 0; it < 2; it++) {
        int idx = it * 512 + t;
        const float* src = IN_SRC(0, idx);
        *(bf16x8*)IN_DST(idx) = pack8(*(const float4*)src, *(const float4*)(src + 4));
    }
    __syncthreads();

    for (int ti = 0; ti < 16; ti++) {
        // prefetch next In tile into regs
        float4 nx[2][2];
        if (ti < 15) {
#pragma unroll
            for (int it = 0; it < 2; it++) {
                const float* src = IN_SRC(ti + 1, it * 512 + t);
                nx[it][0] = *(const float4*)src; nx[it][1] = *(const float4*)(src + 4);
            }
        }

        // MFMA: xf[r] for this thread's (pos = n*16+lr, chs = m*16+lh*4+q)
        f32x4 xf[4];
#pragma unroll
        for (int r = 0; r < 4; r++) xf[r] = (f32x4){0.f, 0.f, 0.f, 0.f};
#pragma unroll
        for (int kk = 0; kk < 2; kk++) {
            int ksl = (kk * 4 + lh) * 16;
#pragma unroll
            for (int r = 0; r < 4; r++) {
                int row = r * 32 + n * 16 + lr;
                bf16x8 bfr = *(const bf16x8*)(lds_in + row * 128 + (ksl ^ ((row & 7) << 4)));
                xf[r] = __builtin_amdgcn_mfma_f32_16x16x32_bf16(afr[r][kk], bfr, xf[r], 0, 0, 0);
            }
        }
#pragma unroll
        for (int r = 0; r < 4; r++) xf[r] += bias[r];

        // stats: pd[r] = sum e^x, pa[r] = sum e^x * xsum (no-max exp, |x|<~5 safe)
        float pd[4] = {0,0,0,0}, pa[4] = {0,0,0,0};
#pragma unroll
        for (int q = 0; q < 4; q++) {
            float xs = xf[0][q] + xf[1][q] + xf[2][q] + xf[3][q];
#pragma unroll
            for (int r = 0; r < 4; r++) {
                float e = __expf(xf[r][q]);
                pd[r] += e; pa[r] += e * xs;
            }
        }
#pragma unroll
        for (int r = 0; r < 4; r++) {
            pd[r] += __shfl_xor(pd[r], 16); pd[r] += __shfl_xor(pd[r], 32);
            pa[r] += __shfl_xor(pa[r], 16); pa[r] += __shfl_xor(pa[r], 32);
        }
        if (lh == 0) {
            float* rb = &redbuf[m][n * 16 + lr][0];
#pragma unroll
            for (int r = 0; r < 4; r++) { rb[r] = pd[r]; rb[4 + r] = pa[r]; }
        }
        // s extraction (q==0): o_out = 1024r + 64j + 16qh + (m*4+lh)
#pragma unroll
        for (int r = 0; r < 4; r++)
            sbuf[n * 16 + lr][r][m * 4 + lh] = (_Float16)xf[r][0];

        barrier_lgkm();

        // Stats partial store (per tile, no atomics)
        if (t < 256) {
            int pos = t >> 3, slot = t & 7;
            float v = redbuf[0][pos][slot] + redbuf[1][pos][slot]
                    + redbuf[2][pos][slot] + redbuf[3][pos][slot];
            Stats[((size_t)(pos0 + ti * 32 + pos) * 64 + (j * 4 + qh)) * 8 + slot] = v;
        }
        // Sb coop store: [32 pos][4 r][16 ch] f16, 8B/thread
        {
            int sp = t >> 4, rr = (t >> 2) & 3, c2 = t & 3;
            *(h4v*)(Sb + (size_t)(pos0 + ti * 32 + sp) * 4096
                       + rr * 1024 + j * 64 + qh * 16 + c2 * 4) =
                *(const h4v*)&sbuf[sp][rr][c2 * 4];
        }
        // write next In tile
        if (ti < 15) {
#pragma unroll
            for (int it = 0; it < 2; it++)
                *(bf16x8*)IN_DST(it * 512 + t) = pack8(nx[it][0], nx[it][1]);
        }
        barrier_lgkm();
    }
}

// ---------------- Kernel Kred: Stats -> Kr[pos][4] ----------------
__global__ __launch_bounds__(256) void fc2_kred(const float* __restrict__ Stats,
                                                float* __restrict__ Kr) {
    int u = blockIdx.x * 256 + threadIdx.x;    // 32768 threads: (pos, slot)
    int pos = u >> 3, s = u & 7;
    const float* sp = Stats + (size_t)pos * 512 + s;
    float acc = 0.f;
#pragma unroll 8
    for (int k = 0; k < 64; k++) acc += sp[k * 8];
    float other = __shfl_xor(acc, 4);
    if (s < 4) Kr[(size_t)pos * 4 + s] = other / acc;   // pa/pd
}

// ---------------- Kernel B: recompute GEMMs, mix + s -> Out ----------------
__global__ __launch_bounds__(512, 2) void fc2_outB(
    const float* __restrict__ In,
    const short* __restrict__ Wp,
    const float* __restrict__ Bias,
    const _Float16* __restrict__ Sb,
    const float* __restrict__ Kr,
    float* __restrict__ Out)         // [NPOS][4096]
{
    __shared__ __align__(16) char lds_in[16384];
    __shared__ __align__(16) char lds_out[8192];       // [32 pos][64 ch] f32 swizzled
    __shared__ float kr_lds[512][4];                   // 8 KB
    GEOM_IDS

    bf16x8 afr[4][2];
#pragma unroll
    for (int r = 0; r < 4; r++)
#pragma unroll
        for (int kk = 0; kk < 2; kk++)
            afr[r][kk] = *(const bf16x8*)(Wp +
                (size_t)((16 * r + j) * 256 + 64 * qh + m * 16 + lr) * 64 + kk * 32 + lh * 8);
    f32x4 bias[4];
#pragma unroll
    for (int r = 0; r < 4; r++)
        bias[r] = *(const f32x4*)(Bias + (16 * r + j) * 256 + 64 * qh + m * 16 + lh * 4);

    // kr for this block's 512 positions
    *(f32x4*)&kr_lds[t][0] = *(const f32x4*)(Kr + (size_t)(pos0 + t) * 4);

#pragma unroll
    for (int it = 0; it < 2; it++) {
        int idx = it * 512 + t;
        const float* src = IN_SRC(0, idx);
        *(bf16x8*)IN_DST(idx) = pack8(*(const float4*)src, *(const float4*)(src + 4));
    }
    __syncthreads();

    for (int ti = 0; ti < 16; ti++) {
        float4 nx[2][2];
        if (ti < 15) {
#pragma unroll
            for (int it = 0; it < 2; it++) {
                const float* src = IN_SRC(ti + 1, it * 512 + t);
                nx[it][0] = *(const float4*)src; nx[it][1] = *(const float4*)(src + 4);
            }
        }

        f32x4 kr4 = *(const f32x4*)&kr_lds[ti * 32 + n * 16 + lr][0];
        f32x4 oacc = (f32x4){0.f, 0.f, 0.f, 0.f};
#pragma unroll
        for (int r = 0; r < 4; r++) {
            f32x4 xf = (f32x4){0.f, 0.f, 0.f, 0.f};
#pragma unroll
            for (int kk = 0; kk < 2; kk++) {
                int ksl = (kk * 4 + lh) * 16;
                int row = r * 32 + n * 16 + lr;
                bf16x8 bfr = *(const bf16x8*)(lds_in + row * 128 + (ksl ^ ((row & 7) << 4)));
                xf = __builtin_amdgcn_mfma_f32_16x16x32_bf16(afr[r][kk], bfr, xf, 0, 0, 0);
            }
            xf += bias[r];
#pragma unroll
            for (int q = 0; q < 4; q++) oacc[q] += xf[q] * kr4[r];
        }
        // mix -> lds_out (swizzled f32x4)
        {
            int pos = n * 16 + lr;
            *(f32x4*)(lds_out + pos * 256 + (((m * 4 + lh) * 16) ^ ((pos & 7) << 4))) = oacc;
        }

        barrier_lgkm();

        // coop: out = mix + s, coalesced 256B/pos
        {
            int sp = t >> 4, ck = t & 15;
            f32x4 mv = *(const f32x4*)(lds_out + sp * 256 + ((ck * 16) ^ ((sp & 7) << 4)));
            h4v sv = *(const h4v*)(Sb + (size_t)(pos0 + ti * 32 + sp) * 4096
                                      + 256 * j + 64 * qh + ck * 4);
            f32x4 ov;
#pragma unroll
            for (int q = 0; q < 4; q++) ov[q] = mv[q] + (float)sv[q];
            *(f32x4*)(Out + (size_t)(pos0 + ti * 32 + sp) * 4096 + 256 * j + 64 * qh + ck * 4) = ov;
        }
        if (ti < 15) {
#pragma unroll
            for (int it = 0; it < 2; it++)
                *(bf16x8*)IN_DST(it * 512 + t) = pack8(nx[it][0], nx[it][1]);
        }
        barrier_lgkm();
    }
}

extern "C" void kernel_launch(void* const* d_in, const int* in_sizes, int n_in,
                              void* d_out, int out_size, void* d_ws, size_t ws_size,
                              hipStream_t stream) {
    const float* In   = (const float*)d_in[0];
    const float* W    = (const float*)d_in[1];
    const float* Bias = (const float*)d_in[2];
    float* Out = (float*)d_out;

    char* ws = (char*)d_ws;
    short*     Wp    = (short*)ws;                     // 2 MB
    _Float16*  Sb    = (_Float16*)(ws + (4u  << 20));  // 32 MB
    float*     Stats = (float*)(ws + (40u << 20));     // 8 MB
    float*     Kr    = (float*)(ws + (52u << 20));     // 64 KB

    fc2_pack  <<<dim3(512), dim3(256), 0, stream>>>(W, Wp);
    fc2_statsA<<<dim3(512), dim3(512), 0, stream>>>(In, Wp, Bias, Sb, Stats);
    fc2_kred  <<<dim3(128), dim3(256), 0, stream>>>(Stats, Kr);
    fc2_outB  <<<dim3(512), dim3(512), 0, stream>>>(In, Wp, Bias, Sb, Kr, Out);
}

// Round 12
// 93.357 us; speedup vs baseline: 1.2077x; 1.0665x over previous
//
#include <hip/hip_runtime.h>

#define CIN  4096
#define OUTR 16384
#define NPOS 4096

typedef __attribute__((ext_vector_type(8))) short    bf16x8;
typedef __attribute__((ext_vector_type(4))) float    f32x4;
typedef __attribute__((ext_vector_type(4))) _Float16 h4v;

__device__ inline short bf16rne(float f) {
    unsigned u = __float_as_uint(f);
    return (short)((u + 0x7FFFu + ((u >> 16) & 1u)) >> 16);
}
__device__ inline bf16x8 pack8(float4 a, float4 b) {
    bf16x8 v;
    v[0]=bf16rne(a.x); v[1]=bf16rne(a.y); v[2]=bf16rne(a.z); v[3]=bf16rne(a.w);
    v[4]=bf16rne(b.x); v[5]=bf16rne(b.y); v[6]=bf16rne(b.z); v[7]=bf16rne(b.w);
    return v;
}

// LDS-only barrier: global stores stay in flight across it
__device__ inline void barrier_lgkm() {
    asm volatile("s_waitcnt lgkmcnt(0)" ::: "memory");
    __builtin_amdgcn_sched_barrier(0);
    __builtin_amdgcn_s_barrier();
    __builtin_amdgcn_sched_barrier(0);
}

// ---------------- pack W f32 -> bf16 ----------------
__global__ __launch_bounds__(256) void fc2_pack(const float* __restrict__ W, short* __restrict__ Wp) {
    int u = blockIdx.x * 256 + threadIdx.x;
    int row = u >> 3, c8 = u & 7;
    const float* s = W + (size_t)row * 64 + c8 * 8;
    float4 a = *(const float4*)s, b = *(const float4*)(s + 4);
    *(bf16x8*)(Wp + (size_t)row * 64 + c8 * 8) = pack8(a, b);
}

// Geometry A/B: 1024 blocks = 16 j x 4 qh x 16 stripes (256 pos = 8 tiles of 32).
// Block: out-ch [256j+64qh, +64), groups g_r=16r+j (K=64), all 4 r in-thread.
// 8 waves: m = w&3 (16-ch tile), n = w>>2 (16-pos half). W frags in regs.
// XCD swizzle (1024 = 8*128, bijective); qh-siblings adjacent -> In L2 reuse.

#define GEOM_IDS \
    const int t = threadIdx.x; \
    const int swz = ((blockIdx.x & 7) << 7) + (blockIdx.x >> 3); \
    const int j = swz >> 6, qh = (swz >> 4) & 3, stripe = swz & 15; \
    const int pos0 = stripe * 256; \
    const int w = t >> 6, l = t & 63, lr = l & 15, lh = l >> 4; \
    const int m = w & 3, n = w >> 2;

#define IN_SRC(ti_, idx_) (In + (size_t)(pos0 + (ti_) * 32 + (((idx_) >> 3) & 31)) * CIN \
                               + (16 * ((idx_) >> 8) + j) * 64 + ((idx_) & 7) * 8)
#define IN_DST(idx_) (lds_in + ((((idx_) >> 8) * 32 + (((idx_) >> 3) & 31)) * 128) \
                             + ((((idx_) & 7) * 16) ^ (((((idx_) >> 3) & 7)) << 4)))

// ---------------- Kernel A: softmax stats + s extraction ----------------
__global__ __launch_bounds__(512, 2) void fc2_statsA(
    const float* __restrict__ In,    // [NPOS][CIN]
    const short* __restrict__ Wp,    // [OUTR][64] bf16
    const float* __restrict__ Bias,  // [OUTR]
    _Float16* __restrict__ Sb,       // [NPOS][4096]
    float* __restrict__ Stats)       // [NPOS][64 jq][8]: pd[4], pa[4]
{
    __shared__ __align__(16) char lds_in[16384];   // [4r][32p][128B] swizzled
    __shared__ float sbufp[32][65];                // padded: bank=(pos+c)%32, conflict-free
    __shared__ float redbuf[4][32][9];             // padded: 9*pos mod 32 distinct
    GEOM_IDS

    bf16x8 afr[4][2];
#pragma unroll
    for (int r = 0; r < 4; r++)
#pragma unroll
        for (int kk = 0; kk < 2; kk++)
            afr[r][kk] = *(const bf16x8*)(Wp +
                (size_t)((16 * r + j) * 256 + 64 * qh + m * 16 + lr) * 64 + kk * 32 + lh * 8);
    f32x4 bias[4];
#pragma unroll
    for (int r = 0; r < 4; r++)
        bias[r] = *(const f32x4*)(Bias + (16 * r + j) * 256 + 64 * qh + m * 16 + lh * 4);

#pragma unroll
    for (int it = 0; it < 2; it++) {
        int idx = it * 512 + t;
        const float* src = IN_SRC(0, idx);
        *(bf16x8*)IN_DST(idx) = pack8(*(const float4*)src, *(const float4*)(src + 4));
    }
    __syncthreads();

    for (int ti = 0; ti < 8; ti++) {
        float4 nx[2][2];
        if (ti < 7) {
#pragma unroll
            for (int it = 0; it < 2; it++) {
                const float* src = IN_SRC(ti + 1, it * 512 + t);
                nx[it][0] = *(const float4*)src; nx[it][1] = *(const float4*)(src + 4);
            }
        }

        f32x4 xf[4];
#pragma unroll
        for (int r = 0; r < 4; r++) xf[r] = (f32x4){0.f, 0.f, 0.f, 0.f};
#pragma unroll
        for (int kk = 0; kk < 2; kk++) {
            int ksl = (kk * 4 + lh) * 16;
#pragma unroll
            for (int r = 0; r < 4; r++) {
                int row = r * 32 + n * 16 + lr;
                bf16x8 bfr = *(const bf16x8*)(lds_in + row * 128 + (ksl ^ ((row & 7) << 4)));
                xf[r] = __builtin_amdgcn_mfma_f32_16x16x32_bf16(afr[r][kk], bfr, xf[r], 0, 0, 0);
            }
        }
#pragma unroll
        for (int r = 0; r < 4; r++) xf[r] += bias[r];

        float pd[4] = {0,0,0,0}, pa[4] = {0,0,0,0};
#pragma unroll
        for (int q = 0; q < 4; q++) {
            float xs = xf[0][q] + xf[1][q] + xf[2][q] + xf[3][q];
#pragma unroll
            for (int r = 0; r < 4; r++) {
                float e = __expf(xf[r][q]);
                pd[r] += e; pa[r] += e * xs;
            }
        }
#pragma unroll
        for (int r = 0; r < 4; r++) {
            pd[r] += __shfl_xor(pd[r], 16); pd[r] += __shfl_xor(pd[r], 32);
            pa[r] += __shfl_xor(pa[r], 16); pa[r] += __shfl_xor(pa[r], 32);
        }
        if (lh == 0) {
            float* rb = &redbuf[m][n * 16 + lr][0];
#pragma unroll
            for (int r = 0; r < 4; r++) { rb[r] = pd[r]; rb[4 + r] = pa[r]; }
        }
        // s extraction (q==0) -> padded f32 sbuf, conflict-free scatter
#pragma unroll
        for (int r = 0; r < 4; r++)
            sbufp[n * 16 + lr][r * 16 + m * 4 + lh] = xf[r][0];

        barrier_lgkm();

        if (t < 256) {
            int pos = t >> 3, slot = t & 7;
            float v = redbuf[0][pos][slot] + redbuf[1][pos][slot]
                    + redbuf[2][pos][slot] + redbuf[3][pos][slot];
            Stats[((size_t)(pos0 + ti * 32 + pos) * 64 + (j * 4 + qh)) * 8 + slot] = v;
        }
        // Sb coop store: thread -> (sp, k): 4 f32 -> h4v, o' = r*1024+j*64+qh*16+ch
        {
            int sp = t >> 4, k = t & 15;
            int rr = k >> 2, c2 = k & 3;
            h4v hv;
#pragma unroll
            for (int i = 0; i < 4; i++)
                hv[i] = (_Float16)sbufp[sp][k * 4 + i];
            *(h4v*)(Sb + (size_t)(pos0 + ti * 32 + sp) * 4096
                       + rr * 1024 + j * 64 + qh * 16 + c2 * 4) = hv;
        }
        if (ti < 7) {
#pragma unroll
            for (int it = 0; it < 2; it++)
                *(bf16x8*)IN_DST(it * 512 + t) = pack8(nx[it][0], nx[it][1]);
        }
        barrier_lgkm();
    }
}

// ---------------- Kernel Kred: Stats -> Kr[pos][4] ----------------
__global__ __launch_bounds__(256) void fc2_kred(const float* __restrict__ Stats,
                                                float* __restrict__ Kr) {
    int u = blockIdx.x * 256 + threadIdx.x;    // 32768 threads: (pos, slot)
    int pos = u >> 3, s = u & 7;
    const float* sp = Stats + (size_t)pos * 512 + s;
    float acc = 0.f;
#pragma unroll 8
    for (int k = 0; k < 64; k++) acc += sp[k * 8];
    float other = __shfl_xor(acc, 4);
    if (s < 4) Kr[(size_t)pos * 4 + s] = other / acc;   // pa/pd
}

// ---------------- Kernel B: recompute GEMMs, mix + s -> Out ----------------
__global__ __launch_bounds__(512, 2) void fc2_outB(
    const float* __restrict__ In,
    const short* __restrict__ Wp,
    const float* __restrict__ Bias,
    const _Float16* __restrict__ Sb,
    const float* __restrict__ Kr,
    float* __restrict__ Out)         // [NPOS][4096]
{
    __shared__ __align__(16) char lds_in[16384];
    __shared__ __align__(16) char lds_out[8192];   // [32 pos][64 ch] f32 swizzled
    __shared__ float kr_lds[256][4];               // 4 KB
    GEOM_IDS

    bf16x8 afr[4][2];
#pragma unroll
    for (int r = 0; r < 4; r++)
#pragma unroll
        for (int kk = 0; kk < 2; kk++)
            afr[r][kk] = *(const bf16x8*)(Wp +
                (size_t)((16 * r + j) * 256 + 64 * qh + m * 16 + lr) * 64 + kk * 32 + lh * 8);
    f32x4 bias[4];
#pragma unroll
    for (int r = 0; r < 4; r++)
        bias[r] = *(const f32x4*)(Bias + (16 * r + j) * 256 + 64 * qh + m * 16 + lh * 4);

    if (t < 256)
        *(f32x4*)&kr_lds[t][0] = *(const f32x4*)(Kr + (size_t)(pos0 + t) * 4);

#pragma unroll
    for (int it = 0; it < 2; it++) {
        int idx = it * 512 + t;
        const float* src = IN_SRC(0, idx);
        *(bf16x8*)IN_DST(idx) = pack8(*(const float4*)src, *(const float4*)(src + 4));
    }
    __syncthreads();

    for (int ti = 0; ti < 8; ti++) {
        float4 nx[2][2];
        if (ti < 7) {
#pragma unroll
            for (int it = 0; it < 2; it++) {
                const float* src = IN_SRC(ti + 1, it * 512 + t);
                nx[it][0] = *(const float4*)src; nx[it][1] = *(const float4*)(src + 4);
            }
        }

        f32x4 kr4 = *(const f32x4*)&kr_lds[ti * 32 + n * 16 + lr][0];
        f32x4 oacc = (f32x4){0.f, 0.f, 0.f, 0.f};
#pragma unroll
        for (int r = 0; r < 4; r++) {
            f32x4 xf = (f32x4){0.f, 0.f, 0.f, 0.f};
#pragma unroll
            for (int kk = 0; kk < 2; kk++) {
                int ksl = (kk * 4 + lh) * 16;
                int row = r * 32 + n * 16 + lr;
                bf16x8 bfr = *(const bf16x8*)(lds_in + row * 128 + (ksl ^ ((row & 7) << 4)));
                xf = __builtin_amdgcn_mfma_f32_16x16x32_bf16(afr[r][kk], bfr, xf, 0, 0, 0);
            }
            xf += bias[r];
#pragma unroll
            for (int q = 0; q < 4; q++) oacc[q] += xf[q] * kr4[r];
        }
        {
            int pos = n * 16 + lr;
            *(f32x4*)(lds_out + pos * 256 + (((m * 4 + lh) * 16) ^ ((pos & 7) << 4))) = oacc;
        }

        barrier_lgkm();

        {
            int sp = t >> 4, ck = t & 15;
            f32x4 mv = *(const f32x4*)(lds_out + sp * 256 + ((ck * 16) ^ ((sp & 7) << 4)));
            h4v sv = *(const h4v*)(Sb + (size_t)(pos0 + ti * 32 + sp) * 4096
                                      + 256 * j + 64 * qh + ck * 4);
            f32x4 ov;
#pragma unroll
            for (int q = 0; q < 4; q++) ov[q] = mv[q] + (float)sv[q];
            *(f32x4*)(Out + (size_t)(pos0 + ti * 32 + sp) * 4096 + 256 * j + 64 * qh + ck * 4) = ov;
        }
        if (ti < 7) {
#pragma unroll
            for (int it = 0; it < 2; it++)
                *(bf16x8*)IN_DST(it * 512 + t) = pack8(nx[it][0], nx[it][1]);
        }
        barrier_lgkm();
    }
}

extern "C" void kernel_launch(void* const* d_in, const int* in_sizes, int n_in,
                              void* d_out, int out_size, void* d_ws, size_t ws_size,
                              hipStream_t stream) {
    const float* In   = (const float*)d_in[0];
    const float* W    = (const float*)d_in[1];
    const float* Bias = (const float*)d_in[2];
    float* Out = (float*)d_out;

    char* ws = (char*)d_ws;
    short*     Wp    = (short*)ws;                     // 2 MB
    _Float16*  Sb    = (_Float16*)(ws + (4u  << 20));  // 32 MB
    float*     Stats = (float*)(ws + (40u << 20));     // 8 MB
    float*     Kr    = (float*)(ws + (52u << 20));     // 64 KB

    fc2_pack  <<<dim3(512),  dim3(256), 0, stream>>>(W, Wp);
    fc2_statsA<<<dim3(1024), dim3(512), 0, stream>>>(In, Wp, Bias, Sb, Stats);
    fc2_kred  <<<dim3(128),  dim3(256), 0, stream>>>(Stats, Kr);
    fc2_outB  <<<dim3(1024), dim3(512), 0, stream>>>(In, Wp, Bias, Sb, Kr, Out);
}

// Round 13
// 81.803 us; speedup vs baseline: 1.3783x; 1.1413x over previous
//
#include <hip/hip_runtime.h>

#define CIN    4096
#define OUTR   16384
#define NPOS   4096
#define CIN_G  64

typedef __attribute__((ext_vector_type(8))) short  bf16x8;
typedef __attribute__((ext_vector_type(4))) float  f32x4;
typedef __attribute__((ext_vector_type(4))) _Float16 h4v;
typedef __attribute__((ext_vector_type(2))) _Float16 h2v;

__device__ inline short bf16rne(float f) {
    unsigned u = __float_as_uint(f);
    return (short)((u + 0x7FFFu + ((u >> 16) & 1u)) >> 16);
}

__device__ inline bf16x8 pack8(float4 a, float4 b) {
    bf16x8 v;
    v[0] = bf16rne(a.x); v[1] = bf16rne(a.y); v[2] = bf16rne(a.z); v[3] = bf16rne(a.w);
    v[4] = bf16rne(b.x); v[5] = bf16rne(b.y); v[6] = bf16rne(b.z); v[7] = bf16rne(b.w);
    return v;
}

// ---------------- Phase 1: pipelined grouped GEMM, 8-wave blocks ----------------
// Grid = 512 blocks = 64 groups x 8 stripes of 512 positions (8 tiles of 64).
// XCD chunk: hw XCD = bid&7 -> each XCD owns 8 whole groups (W L2-local).
// 512 thr = 8 waves; wave w owns 32 channels (g*256 + w*32) x 64 positions.
// Same traffic/prologue as the 4-wave R6 version; 2x waves/CU for latency hiding.
__global__ __launch_bounds__(512, 2) void fc2_phase1(
    const float* __restrict__ In,    // [NPOS][CIN]
    const float* __restrict__ W,     // [OUTR][CIN_G]
    const float* __restrict__ Bias,  // [OUTR]
    _Float16* __restrict__ Y)        // [NPOS][OUTR]
{
    __shared__ __align__(16) char lds[49152];
    char* lds_w   = lds;            // [256 ch][128B] bf16 swizzled (prologue only)
    char* lds_o   = lds;            // [64 pos][512B] f16 swizzled (loop; aliases lds_w)
    char* lds_in0 = lds + 32768;    // [64 pos][128B] bf16 swizzled
    char* lds_in1 = lds + 40960;

    const int t   = threadIdx.x;
    const int swz    = ((blockIdx.x & 7) << 6) + (blockIdx.x >> 3);
    const int g      = swz >> 3;
    const int stripe = swz & 7;
    const int pbase  = stripe * 512;
    const int w  = t >> 6, l = t & 63;
    const int lr = l & 15, lh = l >> 4;

    // ---- prologue: stage W (256x64), In tile 0, bias regs ----
#pragma unroll
    for (int it = 0; it < 4; it++) {
        int q = it * 512 + t;                    // 0..2047
        int row = q >> 3, c8 = q & 7;
        const float* src = W + (size_t)(g * 256 + row) * CIN_G + c8 * 8;
        float4 a = *(const float4*)src;
        float4 b = *(const float4*)(src + 4);
        *(bf16x8*)(lds_w + row * 128 + ((c8 * 16) ^ ((row & 7) << 4))) = pack8(a, b);
    }
    {
        int row = t >> 3, c8 = t & 7;            // 512 units exactly
        const float* src = In + (size_t)(pbase + row) * CIN + g * CIN_G + c8 * 8;
        float4 a = *(const float4*)src;
        float4 b = *(const float4*)(src + 4);
        *(bf16x8*)(lds_in0 + row * 128 + ((c8 * 16) ^ ((row & 7) << 4))) = pack8(a, b);
    }
    float bv[2][4];
#pragma unroll
    for (int m = 0; m < 2; m++) {
        float4 bb = *(const float4*)(Bias + g * 256 + w * 32 + m * 16 + lh * 4);
        bv[m][0] = bb.x; bv[m][1] = bb.y; bv[m][2] = bb.z; bv[m][3] = bb.w;
    }
    __syncthreads();

    // ---- hoist W fragments into registers (lds_w dead afterwards) ----
    bf16x8 afr[2][2];
#pragma unroll
    for (int kk = 0; kk < 2; kk++) {
        const int ksl = (kk * 4 + lh) * 16;
#pragma unroll
        for (int m = 0; m < 2; m++) {
            int row = w * 32 + m * 16 + lr;
            afr[kk][m] = *(const bf16x8*)(lds_w + row * 128 + (ksl ^ ((row & 7) << 4)));
        }
    }

    // ---- main loop over 8 position tiles ----
    for (int i = 0; i < 8; i++) {
        char* bufc = (i & 1) ? lds_in1 : lds_in0;
        char* bufn = (i & 1) ? lds_in0 : lds_in1;
        const int p0 = pbase + i * 64;

        // (a) issue next In tile's global loads first (max latency cover)
        float4 na0, na1;
        int nrow = 0, nc8 = 0;
        if (i < 7) {
            nrow = t >> 3; nc8 = t & 7;
            const float* s0 = In + (size_t)(p0 + 64 + nrow) * CIN + g * CIN_G + nc8 * 8;
            na0 = *(const float4*)s0; na1 = *(const float4*)(s0 + 4);
        }

        // (b) coop-store previous tile's Y
        if (i > 0) {
#pragma unroll
            for (int it = 0; it < 4; it++) {
                int q = it * 512 + t;                // 0..2047
                int pos = q >> 5, c16 = q & 31;
                uint4 v = *(const uint4*)(lds_o + pos * 512 + ((c16 * 16) ^ ((pos & 7) << 4)));
                *(uint4*)(Y + (size_t)(p0 - 64 + pos) * OUTR + g * 256 + c16 * 8) = v;
            }
        }

        // (c) fragments + MFMA: wave w computes 32 ch x 64 pos
        f32x4 acc[2][4];
#pragma unroll
        for (int m = 0; m < 2; m++)
#pragma unroll
            for (int n = 0; n < 4; n++)
                acc[m][n] = (f32x4){0.f, 0.f, 0.f, 0.f};
#pragma unroll
        for (int kk = 0; kk < 2; kk++) {
            const int ksl = (kk * 4 + lh) * 16;
            bf16x8 bfr[4];
#pragma unroll
            for (int n = 0; n < 4; n++) {
                int row = n * 16 + lr;
                bfr[n] = *(const bf16x8*)(bufc + row * 128 + (ksl ^ ((row & 7) << 4)));
            }
#pragma unroll
            for (int m = 0; m < 2; m++)
#pragma unroll
                for (int n = 0; n < 4; n++)
                    acc[m][n] = __builtin_amdgcn_mfma_f32_16x16x32_bf16(afr[kk][m], bfr[n], acc[m][n], 0, 0, 0);
        }

        // (d) pack + LDS-write next In tile
        if (i < 7)
            *(bf16x8*)(bufn + nrow * 128 + ((nc8 * 16) ^ ((nrow & 7) << 4))) = pack8(na0, na1);

        __syncthreads();   // buf[i] reads done; next-tile writes done; lds_o free

        // (e) epilogue: bias + cvt f16 -> lds_o
#pragma unroll
        for (int m = 0; m < 2; m++) {
            const int c_loc = w * 32 + m * 16 + lh * 4;
#pragma unroll
            for (int n = 0; n < 4; n++) {
                const int p = n * 16 + lr;
                h4v hv;
#pragma unroll
                for (int q = 0; q < 4; q++)
                    hv[q] = (_Float16)(acc[m][n][q] + bv[m][q]);
                *(h4v*)(lds_o + p * 512 + ((c_loc * 2) ^ ((p & 7) << 4))) = hv;
            }
        }
        __syncthreads();   // lds_o visible to all
    }

    // ---- tail: store last tile ----
    {
        const int p0 = pbase + 7 * 64;
#pragma unroll
        for (int it = 0; it < 4; it++) {
            int q = it * 512 + t;
            int pos = q >> 5, c16 = q & 31;
            uint4 v = *(const uint4*)(lds_o + pos * 512 + ((c16 * 16) ^ ((pos & 7) << 4)));
            *(uint4*)(Y + (size_t)(p0 + pos) * OUTR + g * 256 + c16 * 8) = v;
        }
    }
}

// ---------------- Phase 2: softmax-attention mix (R6 exact, ~roofline) ----------------
__device__ inline void unpack2(unsigned u, float& a, float& b) {
    h2v h = __builtin_bit_cast(h2v, u);
    a = (float)h[0]; b = (float)h[1];
}

__device__ inline float wredsum(float v) {
#pragma unroll
    for (int off = 32; off; off >>= 1) v += __shfl_xor(v, off);
    return v;
}

__device__ inline int sswz(int a) { return a ^ (((a >> 7) & 7) << 4); }

__global__ __launch_bounds__(256) void fc2_phase2(
    const _Float16* __restrict__ Y,  // [NPOS][OUTR]
    float* __restrict__ Out)         // [NPOS][COUT]
{
    const int p = blockIdx.x;
    const int t = threadIdx.x;
    const int w = t >> 6, l = t & 63;
    const _Float16* yrow = Y + (size_t)p * OUTR;

    __shared__ __align__(16) char s_x[16384];
    __shared__ float redbuf[4][8];

    float x[4][16];
#pragma unroll
    for (int r = 0; r < 4; r++) {
        const uint4* ptr = (const uint4*)(yrow + r * 4096 + t * 16);
        uint4 u0 = ptr[0], u1 = ptr[1];
        unpack2(u0.x, x[r][0],  x[r][1]);
        unpack2(u0.y, x[r][2],  x[r][3]);
        unpack2(u0.z, x[r][4],  x[r][5]);
        unpack2(u0.w, x[r][6],  x[r][7]);
        unpack2(u1.x, x[r][8],  x[r][9]);
        unpack2(u1.y, x[r][10], x[r][11]);
        unpack2(u1.z, x[r][12], x[r][13]);
        unpack2(u1.w, x[r][14], x[r][15]);
    }

#pragma unroll
    for (int r = 0; r < 4; r++) {
        float4 v = make_float4(x[r][0], x[r][4], x[r][8], x[r][12]);
        *(float4*)(s_x + sswz(r * 4096 + t * 16)) = v;
    }

    float dr[4] = {0, 0, 0, 0}, ar[4] = {0, 0, 0, 0};
#pragma unroll
    for (int j = 0; j < 16; j++) {
        float xs = x[0][j] + x[1][j] + x[2][j] + x[3][j];
#pragma unroll
        for (int r = 0; r < 4; r++) {
            float e = __expf(x[r][j]);
            dr[r] += e;
            ar[r] += e * xs;
        }
    }
#pragma unroll
    for (int r = 0; r < 4; r++) { dr[r] = wredsum(dr[r]); ar[r] = wredsum(ar[r]); }
    if (l == 0) {
#pragma unroll
        for (int r = 0; r < 4; r++) { redbuf[w][r] = dr[r]; redbuf[w][4 + r] = ar[r]; }
    }
    __syncthreads();

    float kr[4];
#pragma unroll
    for (int r = 0; r < 4; r++) {
        float d = redbuf[0][r] + redbuf[1][r] + redbuf[2][r] + redbuf[3][r];
        float a = redbuf[0][4 + r] + redbuf[1][4 + r] + redbuf[2][4 + r] + redbuf[3][4 + r];
        kr[r] = a / d;
    }

    float sv[16];
#pragma unroll
    for (int c = 0; c < 4; c++) {
        float4 v = *(const float4*)(s_x + sswz(t * 64 + c * 16));
        sv[4 * c] = v.x; sv[4 * c + 1] = v.y; sv[4 * c + 2] = v.z; sv[4 * c + 3] = v.w;
    }

    float outv[16];
#pragma unroll
    for (int j = 0; j < 16; j++)
        outv[j] = sv[j] + x[0][j] * kr[0] + x[1][j] * kr[1] + x[2][j] * kr[2] + x[3][j] * kr[3];

    float4* op = (float4*)(Out + (size_t)p * 4096 + t * 16);
#pragma unroll
    for (int j = 0; j < 4; j++)
        op[j] = make_float4(outv[4 * j], outv[4 * j + 1], outv[4 * j + 2], outv[4 * j + 3]);
}

extern "C" void kernel_launch(void* const* d_in, const int* in_sizes, int n_in,
                              void* d_out, int out_size, void* d_ws, size_t ws_size,
                              hipStream_t stream) {
    const float* In   = (const float*)d_in[0];
    const float* W    = (const float*)d_in[1];
    const float* Bias = (const float*)d_in[2];
    float* Out = (float*)d_out;
    _Float16* Y = (_Float16*)d_ws;   // NPOS*OUTR*2 = 128 MiB

    fc2_phase1<<<dim3(512), dim3(512), 0, stream>>>(In, W, Bias, Y);
    fc2_phase2<<<dim3(4096), dim3(256), 0, stream>>>(Y, Out);
}

// Round 14
// 80.623 us; speedup vs baseline: 1.3985x; 1.0146x over previous
//
#include <hip/hip_runtime.h>

#define CIN    4096
#define OUTR   16384
#define NPOS   4096
#define CIN_G  64

typedef __attribute__((ext_vector_type(8))) short  bf16x8;
typedef __attribute__((ext_vector_type(4))) float  f32x4;
typedef __attribute__((ext_vector_type(4))) _Float16 h4v;
typedef __attribute__((ext_vector_type(2))) _Float16 h2v;

__device__ inline short bf16rne(float f) {
    unsigned u = __float_as_uint(f);
    return (short)((u + 0x7FFFu + ((u >> 16) & 1u)) >> 16);
}

__device__ inline bf16x8 pack8(float4 a, float4 b) {
    bf16x8 v;
    v[0] = bf16rne(a.x); v[1] = bf16rne(a.y); v[2] = bf16rne(a.z); v[3] = bf16rne(a.w);
    v[4] = bf16rne(b.x); v[5] = bf16rne(b.y); v[6] = bf16rne(b.z); v[7] = bf16rne(b.w);
    return v;
}

// ---------------- Phase 1: pipelined grouped GEMM, 1 barrier/tile ----------------
// Grid = 512 blocks = 64 groups x 8 stripes of 512 positions (8 tiles of 64).
// XCD chunk: each XCD owns 8 whole groups (W L2-local).
// LDS: In 2x8KB + Out 2x32KB = 80KB -> 2 blocks/CU. lds_o double-buffered so the
// Y-store (reads o[prev]) and epilogue (writes o[cur]) need no barrier between.
__global__ __launch_bounds__(256, 2) void fc2_phase1(
    const float* __restrict__ In,    // [NPOS][CIN]
    const float* __restrict__ W,     // [OUTR][CIN_G]
    const float* __restrict__ Bias,  // [OUTR]
    _Float16* __restrict__ Y)        // [NPOS][OUTR]
{
    __shared__ __align__(16) char lds[81920];
    char* lds_o0  = lds;            // [64 pos][512B] f16 swizzled
    char* lds_o1  = lds + 32768;
    char* lds_in0 = lds + 65536;    // [64 pos][128B] bf16 swizzled
    char* lds_in1 = lds + 73728;
    char* lds_w   = lds;            // prologue only (aliases lds_o0/o1)

    const int t   = threadIdx.x;
    const int swz    = ((blockIdx.x & 7) << 6) + (blockIdx.x >> 3);
    const int g      = swz >> 3;
    const int stripe = swz & 7;
    const int pbase  = stripe * 512;
    const int w  = t >> 6, l = t & 63;
    const int lr = l & 15, lh = l >> 4;

    // ---- prologue: stage W (256x64) into lds_w, In tile 0, bias regs ----
#pragma unroll
    for (int it = 0; it < 8; it++) {
        int q = it * 256 + t;
        int row = q >> 3, c8 = q & 7;
        const float* src = W + (size_t)(g * 256 + row) * CIN_G + c8 * 8;
        float4 a = *(const float4*)src;
        float4 b = *(const float4*)(src + 4);
        *(bf16x8*)(lds_w + row * 128 + ((c8 * 16) ^ ((row & 7) << 4))) = pack8(a, b);
    }
#pragma unroll
    for (int it = 0; it < 2; it++) {
        int q = it * 256 + t;
        int row = q >> 3, c8 = q & 7;
        const float* src = In + (size_t)(pbase + row) * CIN + g * CIN_G + c8 * 8;
        float4 a = *(const float4*)src;
        float4 b = *(const float4*)(src + 4);
        *(bf16x8*)(lds_in0 + row * 128 + ((c8 * 16) ^ ((row & 7) << 4))) = pack8(a, b);
    }
    float bv[4][4];
#pragma unroll
    for (int m = 0; m < 4; m++) {
        float4 bb = *(const float4*)(Bias + g * 256 + w * 64 + m * 16 + lh * 4);
        bv[m][0] = bb.x; bv[m][1] = bb.y; bv[m][2] = bb.z; bv[m][3] = bb.w;
    }
    __syncthreads();

    // ---- hoist W fragments into registers (lds_w region freed afterwards) ----
    bf16x8 afr[2][4];
#pragma unroll
    for (int kk = 0; kk < 2; kk++) {
        const int ksl = (kk * 4 + lh) * 16;
#pragma unroll
        for (int m = 0; m < 4; m++) {
            int row = w * 64 + m * 16 + lr;
            afr[kk][m] = *(const bf16x8*)(lds_w + row * 128 + (ksl ^ ((row & 7) << 4)));
        }
    }
    __syncthreads();   // all W reads done before lds_o reuse

    // ---- main loop over 8 position tiles, ONE barrier per tile ----
    for (int i = 0; i < 8; i++) {
        char* bufc = (i & 1) ? lds_in1 : lds_in0;
        char* bufn = (i & 1) ? lds_in0 : lds_in1;
        char* ocur = (i & 1) ? lds_o1  : lds_o0;
        char* oprv = (i & 1) ? lds_o0  : lds_o1;
        const int p0 = pbase + i * 64;

        // (a) issue next In tile's global loads first
        float4 na0, na1, nb0, nb1;
        int nrow0 = 0, nc80 = 0, nrow1 = 0, nc81 = 0;
        if (i < 7) {
            int q0 = t;
            nrow0 = q0 >> 3; nc80 = q0 & 7;
            const float* s0 = In + (size_t)(p0 + 64 + nrow0) * CIN + g * CIN_G + nc80 * 8;
            na0 = *(const float4*)s0; na1 = *(const float4*)(s0 + 4);
            int q1 = 256 + t;
            nrow1 = q1 >> 3; nc81 = q1 & 7;
            const float* s1 = In + (size_t)(p0 + 64 + nrow1) * CIN + g * CIN_G + nc81 * 8;
            nb0 = *(const float4*)s1; nb1 = *(const float4*)(s1 + 4);
        }

        // (b) coop-store previous tile's Y from oprv (disjoint from ocur)
        if (i > 0) {
#pragma unroll
            for (int it = 0; it < 8; it++) {
                int q = it * 256 + t;
                int pos = q >> 5, c16 = q & 31;
                uint4 v = *(const uint4*)(oprv + pos * 512 + ((c16 * 16) ^ ((pos & 7) << 4)));
                *(uint4*)(Y + (size_t)(p0 - 64 + pos) * OUTR + g * 256 + c16 * 8) = v;
            }
        }

        // (c) fragments + MFMA
        f32x4 acc[4][4];
#pragma unroll
        for (int m = 0; m < 4; m++)
#pragma unroll
            for (int n = 0; n < 4; n++)
                acc[m][n] = (f32x4){0.f, 0.f, 0.f, 0.f};
#pragma unroll
        for (int kk = 0; kk < 2; kk++) {
            const int ksl = (kk * 4 + lh) * 16;
            bf16x8 bfr[4];
#pragma unroll
            for (int n = 0; n < 4; n++) {
                int row = n * 16 + lr;
                bfr[n] = *(const bf16x8*)(bufc + row * 128 + (ksl ^ ((row & 7) << 4)));
            }
#pragma unroll
            for (int m = 0; m < 4; m++)
#pragma unroll
                for (int n = 0; n < 4; n++)
                    acc[m][n] = __builtin_amdgcn_mfma_f32_16x16x32_bf16(afr[kk][m], bfr[n], acc[m][n], 0, 0, 0);
        }

        // (d) pack + LDS-write next In tile
        if (i < 7) {
            *(bf16x8*)(bufn + nrow0 * 128 + ((nc80 * 16) ^ ((nrow0 & 7) << 4))) = pack8(na0, na1);
            *(bf16x8*)(bufn + nrow1 * 128 + ((nc81 * 16) ^ ((nrow1 & 7) << 4))) = pack8(nb0, nb1);
        }

        // (e) epilogue: bias + cvt f16 -> ocur (no barrier needed vs (b))
#pragma unroll
        for (int m = 0; m < 4; m++) {
            const int c_loc = w * 64 + m * 16 + lh * 4;
#pragma unroll
            for (int n = 0; n < 4; n++) {
                const int p = n * 16 + lr;
                h4v hv;
#pragma unroll
                for (int q = 0; q < 4; q++)
                    hv[q] = (_Float16)(acc[m][n][q] + bv[m][q]);
                *(h4v*)(ocur + p * 512 + ((c_loc * 2) ^ ((p & 7) << 4))) = hv;
            }
        }

        __syncthreads();   // single drain: bufc reads / bufn+ocur writes / oprv reads
    }

    // ---- tail: store last tile (lds_o of iter 7 = lds_o1) ----
    {
        const int p0 = pbase + 7 * 64;
#pragma unroll
        for (int it = 0; it < 8; it++) {
            int q = it * 256 + t;
            int pos = q >> 5, c16 = q & 31;
            uint4 v = *(const uint4*)(lds_o1 + pos * 512 + ((c16 * 16) ^ ((pos & 7) << 4)));
            *(uint4*)(Y + (size_t)(p0 + pos) * OUTR + g * 256 + c16 * 8) = v;
        }
    }
}

// ---------------- Phase 2: softmax-attention mix (R6 exact, ~roofline) ----------------
__device__ inline void unpack2(unsigned u, float& a, float& b) {
    h2v h = __builtin_bit_cast(h2v, u);
    a = (float)h[0]; b = (float)h[1];
}

__device__ inline float wredsum(float v) {
#pragma unroll
    for (int off = 32; off; off >>= 1) v += __shfl_xor(v, off);
    return v;
}

__device__ inline int sswz(int a) { return a ^ (((a >> 7) & 7) << 4); }

__global__ __launch_bounds__(256) void fc2_phase2(
    const _Float16* __restrict__ Y,  // [NPOS][OUTR]
    float* __restrict__ Out)         // [NPOS][COUT]
{
    const int p = blockIdx.x;
    const int t = threadIdx.x;
    const int w = t >> 6, l = t & 63;
    const _Float16* yrow = Y + (size_t)p * OUTR;

    __shared__ __align__(16) char s_x[16384];
    __shared__ float redbuf[4][8];

    float x[4][16];
#pragma unroll
    for (int r = 0; r < 4; r++) {
        const uint4* ptr = (const uint4*)(yrow + r * 4096 + t * 16);
        uint4 u0 = ptr[0], u1 = ptr[1];
        unpack2(u0.x, x[r][0],  x[r][1]);
        unpack2(u0.y, x[r][2],  x[r][3]);
        unpack2(u0.z, x[r][4],  x[r][5]);
        unpack2(u0.w, x[r][6],  x[r][7]);
        unpack2(u1.x, x[r][8],  x[r][9]);
        unpack2(u1.y, x[r][10], x[r][11]);
        unpack2(u1.z, x[r][12], x[r][13]);
        unpack2(u1.w, x[r][14], x[r][15]);
    }

#pragma unroll
    for (int r = 0; r < 4; r++) {
        float4 v = make_float4(x[r][0], x[r][4], x[r][8], x[r][12]);
        *(float4*)(s_x + sswz(r * 4096 + t * 16)) = v;
    }

    float dr[4] = {0, 0, 0, 0}, ar[4] = {0, 0, 0, 0};
#pragma unroll
    for (int j = 0; j < 16; j++) {
        float xs = x[0][j] + x[1][j] + x[2][j] + x[3][j];
#pragma unroll
        for (int r = 0; r < 4; r++) {
            float e = __expf(x[r][j]);
            dr[r] += e;
            ar[r] += e * xs;
        }
    }
#pragma unroll
    for (int r = 0; r < 4; r++) { dr[r] = wredsum(dr[r]); ar[r] = wredsum(ar[r]); }
    if (l == 0) {
#pragma unroll
        for (int r = 0; r < 4; r++) { redbuf[w][r] = dr[r]; redbuf[w][4 + r] = ar[r]; }
    }
    __syncthreads();

    float kr[4];
#pragma unroll
    for (int r = 0; r < 4; r++) {
        float d = redbuf[0][r] + redbuf[1][r] + redbuf[2][r] + redbuf[3][r];
        float a = redbuf[0][4 + r] + redbuf[1][4 + r] + redbuf[2][4 + r] + redbuf[3][4 + r];
        kr[r] = a / d;
    }

    float sv[16];
#pragma unroll
    for (int c = 0; c < 4; c++) {
        float4 v = *(const float4*)(s_x + sswz(t * 64 + c * 16));
        sv[4 * c] = v.x; sv[4 * c + 1] = v.y; sv[4 * c + 2] = v.z; sv[4 * c + 3] = v.w;
    }

    float outv[16];
#pragma unroll
    for (int j = 0; j < 16; j++)
        outv[j] = sv[j] + x[0][j] * kr[0] + x[1][j] * kr[1] + x[2][j] * kr[2] + x[3][j] * kr[3];

    float4* op = (float4*)(Out + (size_t)p * 4096 + t * 16);
#pragma unroll
    for (int j = 0; j < 4; j++)
        op[j] = make_float4(outv[4 * j], outv[4 * j + 1], outv[4 * j + 2], outv[4 * j + 3]);
}

extern "C" void kernel_launch(void* const* d_in, const int* in_sizes, int n_in,
                              void* d_out, int out_size, void* d_ws, size_t ws_size,
                              hipStream_t stream) {
    const float* In   = (const float*)d_in[0];
    const float* W    = (const float*)d_in[1];
    const float* Bias = (const float*)d_in[2];
    float* Out = (float*)d_out;
    _Float16* Y = (_Float16*)d_ws;   // NPOS*OUTR*2 = 128 MiB

    fc2_phase1<<<dim3(512), dim3(256), 0, stream>>>(In, W, Bias, Y);
    fc2_phase2<<<dim3(4096), dim3(256), 0, stream>>>(Y, Out);
}